// Round 1
// baseline (1949.425 us; speedup 1.0000x reference)
//
#include <hip/hip_runtime.h>

// ---------------------------------------------------------------------------
// FusedSparseLMHead: weighted-mean CE over h @ W^T without materializing logits.
//   h: [4096, 2048] f32, W: [65536, 2048] f32, labels: [4096] int, w: [4096] f32
//   out: scalar f32
// Pipeline:
//   0) convert h -> bf16 (ws)
//   1) per W-segment: convert W rows -> bf16 (ws), run fused GEMM+LSE-partials
//      (tile 128x128, BK=64, m97-style global_load_lds structure)
//   2) exact fp32 label-logit gather-dot
//   3) per-token online-LSE merge of 512 chunk partials -> w*nll
//   4) deterministic single-block weighted mean
// ---------------------------------------------------------------------------

typedef __attribute__((ext_vector_type(8))) short  bf16x8;
typedef __attribute__((ext_vector_type(4))) float  f32x4;
typedef __attribute__((ext_vector_type(8))) float  f32x8;
typedef __attribute__((ext_vector_type(8))) unsigned short u16x8;

#define N_TOK 4096
#define DIM   2048
#define VOCAB 65536
#define BM    128
#define BN    128
#define BK    64
#define NCH   (VOCAB / BN)   // 512 vocab chunks

__device__ __forceinline__ unsigned short f2bf(float x) {
    unsigned u = __float_as_uint(x);
    unsigned r = (u + 0x7fffu + ((u >> 16) & 1u)) >> 16;   // RNE
    return (unsigned short)r;
}

__device__ __forceinline__ void gload_lds16(const void* g, void* l) {
    __builtin_amdgcn_global_load_lds(
        (const __attribute__((address_space(1))) void*)g,
        (__attribute__((address_space(3))) void*)l, 16, 0, 0);
}

// ---------------------------------------------------------------- convert ---
__global__ __launch_bounds__(256) void convert_f32_bf16(
    const float* __restrict__ src, unsigned short* __restrict__ dst, long n)
{
    long i = ((long)blockIdx.x * 256 + threadIdx.x) * 8;
    if (i + 8 > n) return;
    f32x8 v = *(const f32x8*)(src + i);
    u16x8 o;
    #pragma unroll
    for (int j = 0; j < 8; ++j) o[j] = f2bf(v[j]);
    *(u16x8*)(dst + i) = o;
}

// ------------------------------------------------------- GEMM + LSE tiles ---
// C[token][vocab] = sum_k h_bf[token,k] * W_bf[vocab,k]; per-token reduce over
// the 128 vocab cols of this block -> (max, sumexp) partial at [token][chunk].
__global__ __launch_bounds__(256) void gemm_lse(
    const unsigned short* __restrict__ hA,    // [4096][2048] bf16 bits
    const unsigned short* __restrict__ Wb,    // [seg_rows][2048] bf16 bits
    float* __restrict__ part_m, float* __restrict__ part_s, int chunk0)
{
    __shared__ unsigned short A_lds[BM * BK];
    __shared__ unsigned short B_lds[BM * BK];
    __shared__ float red_m[BM * 2];
    __shared__ float red_s[BM * 2];

    const int tid  = threadIdx.x;
    const int lane = tid & 63;
    const int w    = tid >> 6;       // wave 0..3
    const int wm   = w >> 1;         // wave row (token half)
    const int wn   = w & 1;          // wave col (vocab half)
    const long arow0 = (long)blockIdx.y * BM;   // token base
    const long brow0 = (long)blockIdx.x * BM;   // vocab base (within segment)

    f32x4 acc[4][4];
    #pragma unroll
    for (int i = 0; i < 4; ++i)
        #pragma unroll
        for (int j = 0; j < 4; ++j)
            acc[i][j] = (f32x4){0.f, 0.f, 0.f, 0.f};

    const int srow = lane >> 3;             // 0..7 within 8-row slab
    const int scol = (lane & 7) * 8;        // 0..56

    for (int kt = 0; kt < DIM / BK; ++kt) {
        const int k0 = kt * BK;
        #pragma unroll
        for (int q = 0; q < 4; ++q) {
            const int t = w * 4 + q;        // slab 0..15 (8 rows each)
            const long r = t * 8 + srow;
            const int  c = k0 + scol;
            gload_lds16(hA + (arow0 + r) * DIM + c, &A_lds[t * 512]);
            gload_lds16(Wb + (brow0 + r) * DIM + c, &B_lds[t * 512]);
        }
        __syncthreads();   // drains vmcnt -> LDS tile ready
        #pragma unroll
        for (int ks = 0; ks < 2; ++ks) {
            bf16x8 af[4], bfv[4];
            const int kk = ks * 32 + (lane >> 4) * 8;
            #pragma unroll
            for (int f = 0; f < 4; ++f) {
                const int ar = wm * 64 + f * 16 + (lane & 15);
                const int br = wn * 64 + f * 16 + (lane & 15);
                af[f]  = *(const bf16x8*)&A_lds[ar * BK + kk];
                bfv[f] = *(const bf16x8*)&B_lds[br * BK + kk];
            }
            #pragma unroll
            for (int i = 0; i < 4; ++i)
                #pragma unroll
                for (int j = 0; j < 4; ++j)
                    acc[i][j] = __builtin_amdgcn_mfma_f32_16x16x32_bf16(
                        af[i], bfv[j], acc[i][j], 0, 0, 0);
        }
        __syncthreads();   // all reads done before next overwrite
    }

    // epilogue: per-token (max, sumexp) over this block's 128 vocab cols.
    // C layout: row = (lane>>4)*4 + reg, col = lane&15 (per 16x16 fragment).
    #pragma unroll
    for (int i = 0; i < 4; ++i) {
        #pragma unroll
        for (int r = 0; r < 4; ++r) {
            float v0 = acc[i][0][r], v1 = acc[i][1][r];
            float v2 = acc[i][2][r], v3 = acc[i][3][r];
            float mx = fmaxf(fmaxf(v0, v1), fmaxf(v2, v3));
            #pragma unroll
            for (int msk = 1; msk < 16; msk <<= 1)
                mx = fmaxf(mx, __shfl_xor(mx, msk, 64));
            float se = __expf(v0 - mx) + __expf(v1 - mx) +
                       __expf(v2 - mx) + __expf(v3 - mx);
            #pragma unroll
            for (int msk = 1; msk < 16; msk <<= 1)
                se += __shfl_xor(se, msk, 64);
            if ((lane & 15) == 0) {
                const int trow = wm * 64 + i * 16 + (lane >> 4) * 4 + r;
                red_m[trow * 2 + wn] = mx;
                red_s[trow * 2 + wn] = se;
            }
        }
    }
    __syncthreads();
    if (tid < BM) {
        const float m0 = red_m[tid * 2 + 0], m1 = red_m[tid * 2 + 1];
        const float s0 = red_s[tid * 2 + 0], s1 = red_s[tid * 2 + 1];
        const float M = fmaxf(m0, m1);
        const float S = s0 * __expf(m0 - M) + s1 * __expf(m1 - M);
        const long token = arow0 + tid;
        const int  chunk = chunk0 + blockIdx.x;
        part_m[token * NCH + chunk] = M;
        part_s[token * NCH + chunk] = S;
    }
}

// ------------------------------------------------------- exact label dot ----
__global__ __launch_bounds__(256) void label_dot(
    const float* __restrict__ h, const float* __restrict__ W,
    const void* __restrict__ labels, float* __restrict__ lab_logit)
{
    // dtype hedge: int32 data read as int64 yields values >= 2^32 w.h.p.
    bool is64 = true;
    #pragma unroll
    for (int i = 0; i < 8; ++i) {
        long long v = ((const long long*)labels)[i];
        if (v < 0 || v >= VOCAB) is64 = false;
    }
    const int t = blockIdx.x;
    const int lab = is64 ? (int)((const long long*)labels)[t]
                         : ((const int*)labels)[t];
    const float4* hp = (const float4*)(h + (long)t * DIM);
    const float4* wp = (const float4*)(W + (long)lab * DIM);
    float s = 0.f;
    #pragma unroll
    for (int j = 0; j < 2; ++j) {
        const float4 a = hp[threadIdx.x + j * 256];
        const float4 b = wp[threadIdx.x + j * 256];
        s += a.x * b.x + a.y * b.y + a.z * b.z + a.w * b.w;
    }
    #pragma unroll
    for (int msk = 1; msk < 64; msk <<= 1) s += __shfl_xor(s, msk, 64);
    __shared__ float ps[4];
    if ((threadIdx.x & 63) == 0) ps[threadIdx.x >> 6] = s;
    __syncthreads();
    if (threadIdx.x == 0) lab_logit[t] = ps[0] + ps[1] + ps[2] + ps[3];
}

// ---------------------------------------------------- per-token LSE merge ---
__global__ __launch_bounds__(256) void finalize_nll(
    const float* __restrict__ part_m, const float* __restrict__ part_s,
    const float* __restrict__ lab_logit, const float* __restrict__ wts,
    float* __restrict__ wnll)
{
    const int t    = blockIdx.x * 4 + (threadIdx.x >> 6);  // one wave / token
    const int lane = threadIdx.x & 63;
    float m = -3.4e38f, s = 0.f;
    #pragma unroll
    for (int j = 0; j < 8; ++j) {
        const int c = j * 64 + lane;
        const float pm = part_m[(long)t * NCH + c];
        const float ps = part_s[(long)t * NCH + c];
        const float M = fmaxf(m, pm);
        s = s * __expf(m - M) + ps * __expf(pm - M);
        m = M;
    }
    #pragma unroll
    for (int msk = 1; msk < 64; msk <<= 1) {
        const float om = __shfl_xor(m, msk, 64);
        const float os = __shfl_xor(s, msk, 64);
        const float M = fmaxf(m, om);
        s = s * __expf(m - M) + os * __expf(om - M);
        m = M;
    }
    if (lane == 0) {
        const float lse = m + logf(s);
        wnll[t] = wts[t] * (lse - lab_logit[t]);
    }
}

// -------------------------------------------------- deterministic reduce ----
__global__ __launch_bounds__(1024) void final_reduce(
    const float* __restrict__ wnll, const float* __restrict__ wts,
    float* __restrict__ out)
{
    float a = 0.f, b = 0.f;
    #pragma unroll
    for (int j = 0; j < 4; ++j) {
        const int i = threadIdx.x + j * 1024;
        a += wnll[i];
        b += wts[i];
    }
    #pragma unroll
    for (int msk = 1; msk < 64; msk <<= 1) {
        a += __shfl_xor(a, msk, 64);
        b += __shfl_xor(b, msk, 64);
    }
    __shared__ float pa[16], pb[16];
    if ((threadIdx.x & 63) == 0) {
        pa[threadIdx.x >> 6] = a;
        pb[threadIdx.x >> 6] = b;
    }
    __syncthreads();
    if (threadIdx.x == 0) {
        float A = 0.f, B = 0.f;
        #pragma unroll
        for (int i = 0; i < 16; ++i) { A += pa[i]; B += pb[i]; }
        out[0] = A / B;
    }
}

// ----------------------------------------------------------------- launch ---
extern "C" void kernel_launch(void* const* d_in, const int* in_sizes, int n_in,
                              void* d_out, int out_size, void* d_ws, size_t ws_size,
                              hipStream_t stream)
{
    const float* h      = (const float*)d_in[0];
    const void*  labels = d_in[1];
    const float* wts    = (const float*)d_in[2];
    const float* W      = (const float*)d_in[3];
    float* out = (float*)d_out;

    char* ws = (char*)d_ws;
    unsigned short* h_bf     = (unsigned short*)(ws);                          // 16 MB
    float*          part_m   = (float*)(ws + (16u << 20));                     //  8 MB
    float*          part_s   = (float*)(ws + (24u << 20));                     //  8 MB
    float*          lab_logit= (float*)(ws + (32u << 20));                     // 16 KB
    float*          wnll     = (float*)(ws + (32u << 20) + 16384);             // 16 KB
    unsigned short* wseg     = (unsigned short*)(ws + (32u << 20) + 32768);
    const size_t base = (size_t)(32u << 20) + 32768;

    long segmax = 0;
    if (ws_size > base) segmax = (long)((ws_size - base) / ((size_t)DIM * 2));
    segmax &= ~127L;
    if (segmax > VOCAB) segmax = VOCAB;
    if (segmax < 128)   segmax = 128;   // require ws_size >= ~33 MB

    // 0) h -> bf16
    convert_f32_bf16<<<(N_TOK * DIM) / (256 * 8), 256, 0, stream>>>(
        h, h_bf, (long)N_TOK * DIM);

    // 1) segmented W conversion + fused GEMM/LSE partials
    for (long v0 = 0; v0 < VOCAB; v0 += segmax) {
        const long rows = (VOCAB - v0) < segmax ? (VOCAB - v0) : segmax;
        convert_f32_bf16<<<(int)rows, 256, 0, stream>>>(
            W + v0 * DIM, wseg, rows * (long)DIM);
        dim3 grid((unsigned)(rows / BM), N_TOK / BM);
        gemm_lse<<<grid, 256, 0, stream>>>(h_bf, wseg, part_m, part_s,
                                           (int)(v0 / BN));
    }

    // 2) exact label logits (fp32)
    label_dot<<<N_TOK, 256, 0, stream>>>(h, W, labels, lab_logit);

    // 3) per-token LSE merge -> w*nll
    finalize_nll<<<N_TOK / 4, 256, 0, stream>>>(part_m, part_s, lab_logit,
                                                wts, wnll);

    // 4) weighted mean
    final_reduce<<<1, 1024, 0, stream>>>(wnll, wts, out);
}

// Round 2
// 1873.654 us; speedup vs baseline: 1.0404x; 1.0404x over previous
//
#include <hip/hip_runtime.h>

// ---------------------------------------------------------------------------
// FusedSparseLMHead: weighted-mean CE over h @ W^T without materializing logits.
//   h: [4096, 2048] f32, W: [65536, 2048] f32, labels: [4096] int, w: [4096] f32
//   out: scalar f32
// Round 2: token-fastest grid + bijective XCD swizzle (kills 4.3 GB W re-fetch)
//          + both-sides LDS XOR swizzle (kills 4e8 16-way bank conflicts).
// ---------------------------------------------------------------------------

typedef __attribute__((ext_vector_type(8))) short  bf16x8;
typedef __attribute__((ext_vector_type(4))) float  f32x4;
typedef __attribute__((ext_vector_type(8))) float  f32x8;
typedef __attribute__((ext_vector_type(8))) unsigned short u16x8;

#define N_TOK 4096
#define DIM   2048
#define VOCAB 65536
#define BM    128
#define BN    128
#define BK    64
#define NCH   (VOCAB / BN)   // 512 vocab chunks
#define NTB   (N_TOK / BM)   // 32 token blocks

__device__ __forceinline__ unsigned short f2bf(float x) {
    unsigned u = __float_as_uint(x);
    unsigned r = (u + 0x7fffu + ((u >> 16) & 1u)) >> 16;   // RNE
    return (unsigned short)r;
}

__device__ __forceinline__ void gload_lds16(const void* g, void* l) {
    __builtin_amdgcn_global_load_lds(
        (const __attribute__((address_space(1))) void*)g,
        (__attribute__((address_space(3))) void*)l, 16, 0, 0);
}

// ---------------------------------------------------------------- convert ---
__global__ __launch_bounds__(256) void convert_f32_bf16(
    const float* __restrict__ src, unsigned short* __restrict__ dst, long n)
{
    long i = ((long)blockIdx.x * 256 + threadIdx.x) * 8;
    if (i + 8 > n) return;
    f32x8 v = *(const f32x8*)(src + i);
    u16x8 o;
    #pragma unroll
    for (int j = 0; j < 8; ++j) o[j] = f2bf(v[j]);
    *(u16x8*)(dst + i) = o;
}

// ------------------------------------------------------- GEMM + LSE tiles ---
// C[token][vocab] = sum_k h_bf[token,k] * W_bf[vocab,k]; per-token reduce over
// the 128 vocab cols of this block -> (max, sumexp) partial at [token][chunk].
// LDS layout: slab t (8 rows x 64 cols bf16, 1024 B), 16-B chunk c of row r
// holds global chunk (c ^ (r&7))  [linear dest + pre-swizzled source, rule 21].
__global__ __launch_bounds__(256) void gemm_lse(
    const unsigned short* __restrict__ hA,    // [4096][2048] bf16 bits
    const unsigned short* __restrict__ Wb,    // [seg_rows][2048] bf16 bits
    float* __restrict__ part_m, float* __restrict__ part_s, int chunk0)
{
    __shared__ unsigned short A_lds[BM * BK];
    __shared__ unsigned short B_lds[BM * BK];
    __shared__ float red_m[BM * 2];
    __shared__ float red_s[BM * 2];

    const int tid  = threadIdx.x;
    const int lane = tid & 63;
    const int w    = tid >> 6;       // wave 0..3
    const int wm   = w >> 1;         // wave row (token half)
    const int wn   = w & 1;          // wave col (vocab half)

    // bijective XCD-aware remap (m204), then token-fastest decode
    const int nwg  = gridDim.x;
    const int orig = blockIdx.x;
    const int q    = nwg >> 3, r8 = nwg & 7;
    const int xcd  = orig & 7;
    const int wg   = (xcd < r8 ? xcd * (q + 1) : r8 * (q + 1) + (xcd - r8) * q)
                     + (orig >> 3);
    const int tok_blk = wg & (NTB - 1);
    const int voc_blk = wg >> 5;                // NTB == 32

    const long arow0 = (long)tok_blk * BM;      // token base
    const long brow0 = (long)voc_blk * BM;      // vocab base (within segment)

    f32x4 acc[4][4];
    #pragma unroll
    for (int i = 0; i < 4; ++i)
        #pragma unroll
        for (int j = 0; j < 4; ++j)
            acc[i][j] = (f32x4){0.f, 0.f, 0.f, 0.f};

    const int srow = lane >> 3;                     // 0..7 within 8-row slab
    const int scol = ((lane & 7) ^ srow) * 8;       // pre-swizzled source col
    const int swz  = (lane & 7) << 4;               // read-side XOR (bytes)

    for (int kt = 0; kt < DIM / BK; ++kt) {
        const int k0 = kt * BK;
        #pragma unroll
        for (int qq = 0; qq < 4; ++qq) {
            const int t = w * 4 + qq;        // slab 0..15 (8 rows each)
            const long rr = t * 8 + srow;
            const int  c  = k0 + scol;
            gload_lds16(hA + (arow0 + rr) * DIM + c, &A_lds[t * 512]);
            gload_lds16(Wb + (brow0 + rr) * DIM + c, &B_lds[t * 512]);
        }
        __syncthreads();   // drains vmcnt -> LDS tile ready
        #pragma unroll
        for (int ks = 0; ks < 2; ++ks) {
            bf16x8 af[4], bfv[4];
            const int colb = ks * 64 + (lane >> 4) * 16;   // byte col in row
            #pragma unroll
            for (int f = 0; f < 4; ++f) {
                const int ar = wm * 64 + f * 16 + (lane & 15);
                const int br = wn * 64 + f * 16 + (lane & 15);
                af[f]  = *(const bf16x8*)((const char*)A_lds + ar * 128 + (colb ^ swz));
                bfv[f] = *(const bf16x8*)((const char*)B_lds + br * 128 + (colb ^ swz));
            }
            #pragma unroll
            for (int i = 0; i < 4; ++i)
                #pragma unroll
                for (int j = 0; j < 4; ++j)
                    acc[i][j] = __builtin_amdgcn_mfma_f32_16x16x32_bf16(
                        af[i], bfv[j], acc[i][j], 0, 0, 0);
        }
        __syncthreads();   // all reads done before next overwrite
    }

    // epilogue: per-token (max, sumexp) over this block's 128 vocab cols.
    // C layout: row = (lane>>4)*4 + reg, col = lane&15 (per 16x16 fragment).
    #pragma unroll
    for (int i = 0; i < 4; ++i) {
        #pragma unroll
        for (int r = 0; r < 4; ++r) {
            float v0 = acc[i][0][r], v1 = acc[i][1][r];
            float v2 = acc[i][2][r], v3 = acc[i][3][r];
            float mx = fmaxf(fmaxf(v0, v1), fmaxf(v2, v3));
            #pragma unroll
            for (int msk = 1; msk < 16; msk <<= 1)
                mx = fmaxf(mx, __shfl_xor(mx, msk, 64));
            float se = __expf(v0 - mx) + __expf(v1 - mx) +
                       __expf(v2 - mx) + __expf(v3 - mx);
            #pragma unroll
            for (int msk = 1; msk < 16; msk <<= 1)
                se += __shfl_xor(se, msk, 64);
            if ((lane & 15) == 0) {
                const int trow = wm * 64 + i * 16 + (lane >> 4) * 4 + r;
                red_m[trow * 2 + wn] = mx;
                red_s[trow * 2 + wn] = se;
            }
        }
    }
    __syncthreads();
    if (tid < BM) {
        const float m0 = red_m[tid * 2 + 0], m1 = red_m[tid * 2 + 1];
        const float s0 = red_s[tid * 2 + 0], s1 = red_s[tid * 2 + 1];
        const float M = fmaxf(m0, m1);
        const float S = s0 * __expf(m0 - M) + s1 * __expf(m1 - M);
        const long token = arow0 + tid;
        const int  chunk = chunk0 + voc_blk;
        part_m[token * NCH + chunk] = M;
        part_s[token * NCH + chunk] = S;
    }
}

// ------------------------------------------------------- exact label dot ----
__global__ __launch_bounds__(256) void label_dot(
    const float* __restrict__ h, const float* __restrict__ W,
    const void* __restrict__ labels, float* __restrict__ lab_logit)
{
    // dtype hedge: int32 data read as int64 yields values >= 2^32 w.h.p.
    bool is64 = true;
    #pragma unroll
    for (int i = 0; i < 8; ++i) {
        long long v = ((const long long*)labels)[i];
        if (v < 0 || v >= VOCAB) is64 = false;
    }
    const int t = blockIdx.x;
    const int lab = is64 ? (int)((const long long*)labels)[t]
                         : ((const int*)labels)[t];
    const float4* hp = (const float4*)(h + (long)t * DIM);
    const float4* wp = (const float4*)(W + (long)lab * DIM);
    float s = 0.f;
    #pragma unroll
    for (int j = 0; j < 2; ++j) {
        const float4 a = hp[threadIdx.x + j * 256];
        const float4 b = wp[threadIdx.x + j * 256];
        s += a.x * b.x + a.y * b.y + a.z * b.z + a.w * b.w;
    }
    #pragma unroll
    for (int msk = 1; msk < 64; msk <<= 1) s += __shfl_xor(s, msk, 64);
    __shared__ float ps[4];
    if ((threadIdx.x & 63) == 0) ps[threadIdx.x >> 6] = s;
    __syncthreads();
    if (threadIdx.x == 0) lab_logit[t] = ps[0] + ps[1] + ps[2] + ps[3];
}

// ---------------------------------------------------- per-token LSE merge ---
__global__ __launch_bounds__(256) void finalize_nll(
    const float* __restrict__ part_m, const float* __restrict__ part_s,
    const float* __restrict__ lab_logit, const float* __restrict__ wts,
    float* __restrict__ wnll)
{
    const int t    = blockIdx.x * 4 + (threadIdx.x >> 6);  // one wave / token
    const int lane = threadIdx.x & 63;
    float m = -3.4e38f, s = 0.f;
    #pragma unroll
    for (int j = 0; j < 8; ++j) {
        const int c = j * 64 + lane;
        const float pm = part_m[(long)t * NCH + c];
        const float ps = part_s[(long)t * NCH + c];
        const float M = fmaxf(m, pm);
        s = s * __expf(m - M) + ps * __expf(pm - M);
        m = M;
    }
    #pragma unroll
    for (int msk = 1; msk < 64; msk <<= 1) {
        const float om = __shfl_xor(m, msk, 64);
        const float os = __shfl_xor(s, msk, 64);
        const float M = fmaxf(m, om);
        s = s * __expf(m - M) + os * __expf(om - M);
        m = M;
    }
    if (lane == 0) {
        const float lse = m + logf(s);
        wnll[t] = wts[t] * (lse - lab_logit[t]);
    }
}

// -------------------------------------------------- deterministic reduce ----
__global__ __launch_bounds__(1024) void final_reduce(
    const float* __restrict__ wnll, const float* __restrict__ wts,
    float* __restrict__ out)
{
    float a = 0.f, b = 0.f;
    #pragma unroll
    for (int j = 0; j < 4; ++j) {
        const int i = threadIdx.x + j * 1024;
        a += wnll[i];
        b += wts[i];
    }
    #pragma unroll
    for (int msk = 1; msk < 64; msk <<= 1) {
        a += __shfl_xor(a, msk, 64);
        b += __shfl_xor(b, msk, 64);
    }
    __shared__ float pa[16], pb[16];
    if ((threadIdx.x & 63) == 0) {
        pa[threadIdx.x >> 6] = a;
        pb[threadIdx.x >> 6] = b;
    }
    __syncthreads();
    if (threadIdx.x == 0) {
        float A = 0.f, B = 0.f;
        #pragma unroll
        for (int i = 0; i < 16; ++i) { A += pa[i]; B += pb[i]; }
        out[0] = A / B;
    }
}

// ----------------------------------------------------------------- launch ---
extern "C" void kernel_launch(void* const* d_in, const int* in_sizes, int n_in,
                              void* d_out, int out_size, void* d_ws, size_t ws_size,
                              hipStream_t stream)
{
    const float* h      = (const float*)d_in[0];
    const void*  labels = d_in[1];
    const float* wts    = (const float*)d_in[2];
    const float* W      = (const float*)d_in[3];
    float* out = (float*)d_out;

    char* ws = (char*)d_ws;
    unsigned short* h_bf     = (unsigned short*)(ws);                          // 16 MB
    float*          part_m   = (float*)(ws + (16u << 20));                     //  8 MB
    float*          part_s   = (float*)(ws + (24u << 20));                     //  8 MB
    float*          lab_logit= (float*)(ws + (32u << 20));                     // 16 KB
    float*          wnll     = (float*)(ws + (32u << 20) + 16384);             // 16 KB
    unsigned short* wseg     = (unsigned short*)(ws + (32u << 20) + 32768);
    const size_t base = (size_t)(32u << 20) + 32768;

    long segmax = 0;
    if (ws_size > base) segmax = (long)((ws_size - base) / ((size_t)DIM * 2));
    segmax &= ~127L;
    if (segmax > VOCAB) segmax = VOCAB;
    if (segmax < 128)   segmax = 128;   // require ws_size >= ~33 MB

    // 0) h -> bf16
    convert_f32_bf16<<<(N_TOK * DIM) / (256 * 8), 256, 0, stream>>>(
        h, h_bf, (long)N_TOK * DIM);

    // 1) segmented W conversion + fused GEMM/LSE partials
    for (long v0 = 0; v0 < VOCAB; v0 += segmax) {
        const long rows = (VOCAB - v0) < segmax ? (VOCAB - v0) : segmax;
        convert_f32_bf16<<<(int)(rows * DIM / (256 * 8)), 256, 0, stream>>>(
            W + v0 * DIM, wseg, rows * (long)DIM);
        const int nwg = (int)(rows / BM) * NTB;
        gemm_lse<<<nwg, 256, 0, stream>>>(h_bf, wseg, part_m, part_s,
                                          (int)(v0 / BN));
    }

    // 2) exact label logits (fp32)
    label_dot<<<N_TOK, 256, 0, stream>>>(h, W, labels, lab_logit);

    // 3) per-token LSE merge -> w*nll
    finalize_nll<<<N_TOK / 4, 256, 0, stream>>>(part_m, part_s, lab_logit,
                                                wts, wnll);

    // 4) weighted mean
    final_reduce<<<1, 1024, 0, stream>>>(wnll, wts, out);
}

// Round 3
// 1692.737 us; speedup vs baseline: 1.1516x; 1.1069x over previous
//
#include <hip/hip_runtime.h>

// ---------------------------------------------------------------------------
// FusedSparseLMHead: weighted-mean CE over h @ W^T without materializing logits.
//   h: [4096, 2048] f32, W: [65536, 2048] f32, labels: [4096] int, w: [4096] f32
// Round 3: 256x256 8-phase GEMM (T1 XCD swizzle + T2 LDS XOR swizzle +
//          T3/T4 counted-vmcnt 4-phase/K-step pipeline + T5 setprio).
// Staging ring: per operand 4 half-tile slots (128x64 bf16, slot=(t&1)*2+half).
//   phase 0 of K-step t: stage A0(t+1)   (slot freed at end of t-1)
//   phase 1:             stage A1(t+1)
//   phase 2:             stage B0(t+2)   (B slots read only in phase 0 of t)
//   phase 3:             stage B1(t+2)
// Boundary wait vmcnt(4): newest 2 half-tiles (B(t+2)) may stay in flight.
// ---------------------------------------------------------------------------

typedef __attribute__((ext_vector_type(8))) short  bf16x8;
typedef __attribute__((ext_vector_type(4))) float  f32x4;
typedef __attribute__((ext_vector_type(8))) float  f32x8;
typedef __attribute__((ext_vector_type(8))) unsigned short u16x8;

#define N_TOK 4096
#define DIM   2048
#define VOCAB 65536
#define BM    256
#define BN    256
#define BK    64
#define NT    (DIM / BK)     // 32 K-steps
#define NCH   (VOCAB / BN)   // 256 vocab chunks
#define NTB   (N_TOK / BM)   // 16 token blocks

__device__ __forceinline__ unsigned short f2bf(float x) {
    unsigned u = __float_as_uint(x);
    unsigned r = (u + 0x7fffu + ((u >> 16) & 1u)) >> 16;   // RNE
    return (unsigned short)r;
}

__device__ __forceinline__ void gload_lds16(const void* g, void* l) {
    __builtin_amdgcn_global_load_lds(
        (const __attribute__((address_space(1))) void*)g,
        (__attribute__((address_space(3))) void*)l, 16, 0, 0);
}

__device__ __forceinline__ void bar() {
    asm volatile("" ::: "memory");
    __builtin_amdgcn_s_barrier();
    asm volatile("" ::: "memory");
}

// stage one 128x64 half-tile (16 KB): 512 threads x 2 loads x 16 B.
// LDS chunk c of row r receives global chunk (c ^ (r&7))  [pre-swizzled src,
// linear dest -- rule 21]; dest ptr must be wave-uniform (HW adds lane*16).
__device__ __forceinline__ void stage_half(
    const unsigned short* __restrict__ g, unsigned short* slot, int w, int lane)
{
    #pragma unroll
    for (int j = 0; j < 2; ++j) {
        const int idx = j * 512 + w * 64 + lane;
        const int r = idx >> 3, c = idx & 7;
        gload_lds16(g + (long)r * DIM + (c ^ (r & 7)) * 8,
                    slot + (j * 512 + w * 64) * 8);
    }
}

// ---------------------------------------------------------------- convert ---
__global__ __launch_bounds__(256) void convert_f32_bf16(
    const float* __restrict__ src, unsigned short* __restrict__ dst, long n)
{
    long i = ((long)blockIdx.x * 256 + threadIdx.x) * 8;
    if (i + 8 > n) return;
    f32x8 v = *(const f32x8*)(src + i);
    u16x8 o;
    #pragma unroll
    for (int j = 0; j < 8; ++j) o[j] = f2bf(v[j]);
    *(u16x8*)(dst + i) = o;
}

// ------------------------------------------------- 256^2 8-phase GEMM+LSE ---
__global__ __launch_bounds__(512, 2) void gemm_lse(
    const unsigned short* __restrict__ hA,    // [4096][2048] bf16 bits
    const unsigned short* __restrict__ Wb,    // [seg_rows][2048] bf16 bits
    float* __restrict__ part_m, float* __restrict__ part_s, int chunk0)
{
    __shared__ unsigned short A_lds[4][128 * 64];
    __shared__ unsigned short B_lds[4][128 * 64];
    __shared__ float red_m[256 * 4];
    __shared__ float red_s[256 * 4];

    const int tid  = threadIdx.x;
    const int lane = tid & 63;
    const int w    = tid >> 6;       // wave 0..7
    const int wm   = w >> 2;         // 0..1 : token half (128 rows)
    const int wn   = w & 3;          // 0..3 : vocab quarter (64 cols)

    // bijective XCD-aware remap (m204), token-fastest decode
    const int nwg  = gridDim.x;
    const int orig = blockIdx.x;
    const int q8 = nwg >> 3, r8 = nwg & 7;
    const int xcd = orig & 7;
    const int wg  = (xcd < r8 ? xcd * (q8 + 1) : r8 * (q8 + 1) + (xcd - r8) * q8)
                    + (orig >> 3);
    const int tok_blk = wg & (NTB - 1);
    const int voc_blk = wg >> 4;                 // NTB == 16

    const long arow0 = (long)tok_blk * BM;
    const long brow0 = (long)voc_blk * BM;
    const unsigned short* Ab = hA + arow0 * DIM;
    const unsigned short* Bb = Wb + brow0 * DIM;

    f32x4 acc[8][4];
    #pragma unroll
    for (int i = 0; i < 8; ++i)
        #pragma unroll
        for (int j = 0; j < 4; ++j)
            acc[i][j] = (f32x4){0.f, 0.f, 0.f, 0.f};

    // prologue: K-step 0 (A0,A1,B0,B1) + B(1); A(1) is staged inside t=0.
    stage_half(Ab,                 &A_lds[0][0], w, lane);
    stage_half(Ab + 128 * DIM,     &A_lds[1][0], w, lane);
    stage_half(Bb,                 &B_lds[0][0], w, lane);
    stage_half(Bb + 128 * DIM,     &B_lds[1][0], w, lane);
    stage_half(Bb + 64,            &B_lds[2][0], w, lane);
    stage_half(Bb + 128 * DIM + 64,&B_lds[3][0], w, lane);
    asm volatile("s_waitcnt vmcnt(4)" ::: "memory");   // K-step 0 tiles ready
    bar();

    const int swz   = (lane & 7) << 4;        // read-side XOR (row&7 == lane&7)
    const int colb0 = (lane >> 4) * 16;       // kk byte col base
    const int lrow  = lane & 15;

    for (int t = 0; t < NT; ++t) {
        const int p = (t & 1) * 2;
        const char* Ah = (const char*)&A_lds[p + wm][0];
        const char* Bh = (const char*)&B_lds[p + (wn >> 1)][0];
        const int  brB = (wn & 1) * 64;
        bf16x8 bfr[4][2];

        #pragma unroll
        for (int q = 0; q < 4; ++q) {
            // --- ds-load register subtile ---
            bf16x8 afr[2][2];
            #pragma unroll
            for (int f = 0; f < 2; ++f) {
                const int row = q * 32 + f * 16 + lrow;
                #pragma unroll
                for (int kk = 0; kk < 2; ++kk)
                    afr[f][kk] = *(const bf16x8*)(Ah + row * 128 +
                                                  ((kk * 64 + colb0) ^ swz));
            }
            if (q == 0) {
                #pragma unroll
                for (int n = 0; n < 4; ++n) {
                    const int row = brB + n * 16 + lrow;
                    #pragma unroll
                    for (int kk = 0; kk < 2; ++kk)
                        bfr[n][kk] = *(const bf16x8*)(Bh + row * 128 +
                                                      ((kk * 64 + colb0) ^ swz));
                }
            }
            // --- stage one half-tile for a future K-step ---
            if (q == 0 && t + 1 < NT)
                stage_half(Ab + (t + 1) * 64,
                           &A_lds[((t + 1) & 1) * 2 + 0][0], w, lane);
            if (q == 1 && t + 1 < NT)
                stage_half(Ab + 128 * DIM + (t + 1) * 64,
                           &A_lds[((t + 1) & 1) * 2 + 1][0], w, lane);
            if (q == 2 && t + 2 < NT)
                stage_half(Bb + (t + 2) * 64, &B_lds[p + 0][0], w, lane);
            if (q == 3 && t + 2 < NT)
                stage_half(Bb + 128 * DIM + (t + 2) * 64,
                           &B_lds[p + 1][0], w, lane);

            bar();                              // all reads+stages issued
            __builtin_amdgcn_s_setprio(1);
            #pragma unroll
            for (int kk = 0; kk < 2; ++kk)
                #pragma unroll
                for (int f = 0; f < 2; ++f)
                    #pragma unroll
                    for (int n = 0; n < 4; ++n)
                        acc[q * 2 + f][n] = __builtin_amdgcn_mfma_f32_16x16x32_bf16(
                            afr[f][kk], bfr[n][kk], acc[q * 2 + f][n], 0, 0, 0);
            __builtin_amdgcn_s_setprio(0);
            if (q < 3) bar();                   // phase end
        }
        // K-step boundary: allow newest 2 half-tiles (B(t+2)) in flight.
        if (t < NT - 2) asm volatile("s_waitcnt vmcnt(4)" ::: "memory");
        else            asm volatile("s_waitcnt vmcnt(0)" ::: "memory");
        bar();
    }

    // ---- epilogue: per-token (max, sumexp) over this block's 256 cols ----
    // C frag layout: row = mf*16 + (lane>>4)*4 + reg, col = nf*16 + (lane&15).
    #pragma unroll
    for (int mf = 0; mf < 8; ++mf) {
        #pragma unroll
        for (int r = 0; r < 4; ++r) {
            float v0 = acc[mf][0][r], v1 = acc[mf][1][r];
            float v2 = acc[mf][2][r], v3 = acc[mf][3][r];
            float mx = fmaxf(fmaxf(v0, v1), fmaxf(v2, v3));
            #pragma unroll
            for (int msk = 1; msk < 16; msk <<= 1)
                mx = fmaxf(mx, __shfl_xor(mx, msk, 64));
            float se = __expf(v0 - mx) + __expf(v1 - mx) +
                       __expf(v2 - mx) + __expf(v3 - mx);
            #pragma unroll
            for (int msk = 1; msk < 16; msk <<= 1)
                se += __shfl_xor(se, msk, 64);
            if ((lane & 15) == 0) {
                const int row = wm * 128 + mf * 16 + (lane >> 4) * 4 + r;
                red_m[row * 4 + wn] = mx;
                red_s[row * 4 + wn] = se;
            }
        }
    }
    __syncthreads();
    if (tid < 256) {
        float M = red_m[tid * 4], S = red_s[tid * 4];
        #pragma unroll
        for (int j = 1; j < 4; ++j) {
            const float m2 = red_m[tid * 4 + j], s2 = red_s[tid * 4 + j];
            const float Mn = fmaxf(M, m2);
            S = S * __expf(M - Mn) + s2 * __expf(m2 - Mn);
            M = Mn;
        }
        part_m[(arow0 + tid) * NCH + chunk0 + voc_blk] = M;
        part_s[(arow0 + tid) * NCH + chunk0 + voc_blk] = S;
    }
}

// ------------------------------------------------------- exact label dot ----
__global__ __launch_bounds__(256) void label_dot(
    const float* __restrict__ h, const float* __restrict__ W,
    const void* __restrict__ labels, float* __restrict__ lab_logit)
{
    bool is64 = true;
    #pragma unroll
    for (int i = 0; i < 8; ++i) {
        long long v = ((const long long*)labels)[i];
        if (v < 0 || v >= VOCAB) is64 = false;
    }
    const int t = blockIdx.x;
    const int lab = is64 ? (int)((const long long*)labels)[t]
                         : ((const int*)labels)[t];
    const float4* hp = (const float4*)(h + (long)t * DIM);
    const float4* wp = (const float4*)(W + (long)lab * DIM);
    float s = 0.f;
    #pragma unroll
    for (int j = 0; j < 2; ++j) {
        const float4 a = hp[threadIdx.x + j * 256];
        const float4 b = wp[threadIdx.x + j * 256];
        s += a.x * b.x + a.y * b.y + a.z * b.z + a.w * b.w;
    }
    #pragma unroll
    for (int msk = 1; msk < 64; msk <<= 1) s += __shfl_xor(s, msk, 64);
    __shared__ float ps[4];
    if ((threadIdx.x & 63) == 0) ps[threadIdx.x >> 6] = s;
    __syncthreads();
    if (threadIdx.x == 0) lab_logit[t] = ps[0] + ps[1] + ps[2] + ps[3];
}

// ---------------------------------------------------- per-token LSE merge ---
__global__ __launch_bounds__(256) void finalize_nll(
    const float* __restrict__ part_m, const float* __restrict__ part_s,
    const float* __restrict__ lab_logit, const float* __restrict__ wts,
    float* __restrict__ wnll)
{
    const int t    = blockIdx.x * 4 + (threadIdx.x >> 6);  // one wave / token
    const int lane = threadIdx.x & 63;
    float m = -3.4e38f, s = 0.f;
    #pragma unroll
    for (int j = 0; j < 4; ++j) {
        const int c = j * 64 + lane;
        const float pm = part_m[(long)t * NCH + c];
        const float ps = part_s[(long)t * NCH + c];
        const float M = fmaxf(m, pm);
        s = s * __expf(m - M) + ps * __expf(pm - M);
        m = M;
    }
    #pragma unroll
    for (int msk = 1; msk < 64; msk <<= 1) {
        const float om = __shfl_xor(m, msk, 64);
        const float os = __shfl_xor(s, msk, 64);
        const float M = fmaxf(m, om);
        s = s * __expf(m - M) + os * __expf(om - M);
        m = M;
    }
    if (lane == 0) {
        const float lse = m + logf(s);
        wnll[t] = wts[t] * (lse - lab_logit[t]);
    }
}

// -------------------------------------------------- deterministic reduce ----
__global__ __launch_bounds__(1024) void final_reduce(
    const float* __restrict__ wnll, const float* __restrict__ wts,
    float* __restrict__ out)
{
    float a = 0.f, b = 0.f;
    #pragma unroll
    for (int j = 0; j < 4; ++j) {
        const int i = threadIdx.x + j * 1024;
        a += wnll[i];
        b += wts[i];
    }
    #pragma unroll
    for (int msk = 1; msk < 64; msk <<= 1) {
        a += __shfl_xor(a, msk, 64);
        b += __shfl_xor(b, msk, 64);
    }
    __shared__ float pa[16], pb[16];
    if ((threadIdx.x & 63) == 0) {
        pa[threadIdx.x >> 6] = a;
        pb[threadIdx.x >> 6] = b;
    }
    __syncthreads();
    if (threadIdx.x == 0) {
        float A = 0.f, B = 0.f;
        #pragma unroll
        for (int i = 0; i < 16; ++i) { A += pa[i]; B += pb[i]; }
        out[0] = A / B;
    }
}

// ----------------------------------------------------------------- launch ---
extern "C" void kernel_launch(void* const* d_in, const int* in_sizes, int n_in,
                              void* d_out, int out_size, void* d_ws, size_t ws_size,
                              hipStream_t stream)
{
    const float* h      = (const float*)d_in[0];
    const void*  labels = d_in[1];
    const float* wts    = (const float*)d_in[2];
    const float* W      = (const float*)d_in[3];
    float* out = (float*)d_out;

    char* ws = (char*)d_ws;
    unsigned short* h_bf      = (unsigned short*)(ws);                 // 16 MB
    float*          part_m    = (float*)(ws + (16u << 20));            //  4 MB
    float*          part_s    = (float*)(ws + (24u << 20));            //  4 MB
    float*          lab_logit = (float*)(ws + (32u << 20));            // 16 KB
    float*          wnll      = (float*)(ws + (32u << 20) + 16384);    // 16 KB
    unsigned short* wseg      = (unsigned short*)(ws + (32u << 20) + 32768);
    const size_t base = (size_t)(32u << 20) + 32768;

    long segmax = 0;
    if (ws_size > base) segmax = (long)((ws_size - base) / ((size_t)DIM * 2));
    segmax &= ~255L;
    if (segmax > VOCAB) segmax = VOCAB;
    if (segmax < 256)   segmax = 256;   // require ws_size >= ~34 MB

    // 0) h -> bf16
    convert_f32_bf16<<<(N_TOK * DIM) / (256 * 8), 256, 0, stream>>>(
        h, h_bf, (long)N_TOK * DIM);

    // 1) segmented W conversion + fused GEMM/LSE partials
    for (long v0 = 0; v0 < VOCAB; v0 += segmax) {
        const long rows = (VOCAB - v0) < segmax ? (VOCAB - v0) : segmax;
        convert_f32_bf16<<<(int)(rows * DIM / (256 * 8)), 256, 0, stream>>>(
            W + v0 * DIM, wseg, rows * (long)DIM);
        const int nwg = (int)(rows / BM) * NTB;
        gemm_lse<<<nwg, 512, 0, stream>>>(h_bf, wseg, part_m, part_s,
                                          (int)(v0 / BN));
    }

    // 2) exact label logits (fp32)
    label_dot<<<N_TOK, 256, 0, stream>>>(h, W, labels, lab_logit);

    // 3) per-token LSE merge -> w*nll
    finalize_nll<<<N_TOK / 4, 256, 0, stream>>>(part_m, part_s, lab_logit,
                                                wts, wnll);

    // 4) weighted mean
    final_reduce<<<1, 1024, 0, stream>>>(wnll, wts, out);
}

// Round 4
// 1625.112 us; speedup vs baseline: 1.1996x; 1.0416x over previous
//
#include <hip/hip_runtime.h>

// ---------------------------------------------------------------------------
// FusedSparseLMHead: weighted-mean CE over h @ W^T without materializing logits.
//   h: [4096, 2048] f32, W: [65536, 2048] f32, labels: [4096] int, w: [4096] f32
// Round 4: 256x256 GEMM, 2 barriers/K-step, read-ahead software pipeline:
//   region1: reads(q0,q1)+B-frags | stage A(t+1) | MFMA q0
//   midbar   (B reads complete via q0-MFMA data dep before any B restage)
//   region2: reads(q2) | stage B0(t+2) | MFMA q1 | reads(q3) | stage B1(t+2)
//            | MFMA q2 | MFMA q3
//   boundary: vmcnt(4) (B(t+2) floats) + bar
// ---------------------------------------------------------------------------

typedef __attribute__((ext_vector_type(8))) short  bf16x8;
typedef __attribute__((ext_vector_type(4))) float  f32x4;
typedef __attribute__((ext_vector_type(8))) float  f32x8;
typedef __attribute__((ext_vector_type(8))) unsigned short u16x8;

#define N_TOK 4096
#define DIM   2048
#define VOCAB 65536
#define BM    256
#define BN    256
#define BK    64
#define NT    (DIM / BK)     // 32 K-steps
#define NCH   (VOCAB / BN)   // 256 vocab chunks
#define NTB   (N_TOK / BM)   // 16 token blocks

__device__ __forceinline__ unsigned short f2bf(float x) {
    unsigned u = __float_as_uint(x);
    unsigned r = (u + 0x7fffu + ((u >> 16) & 1u)) >> 16;   // RNE
    return (unsigned short)r;
}

__device__ __forceinline__ void gload_lds16(const void* g, void* l) {
    __builtin_amdgcn_global_load_lds(
        (const __attribute__((address_space(1))) void*)g,
        (__attribute__((address_space(3))) void*)l, 16, 0, 0);
}

__device__ __forceinline__ void bar() {
    asm volatile("" ::: "memory");
    __builtin_amdgcn_s_barrier();
    asm volatile("" ::: "memory");
}

// stage one 128x64 half-tile (16 KB): 512 threads x 2 loads x 16 B.
// LDS chunk c of row r receives global chunk (c ^ (r&7))  [pre-swizzled src,
// linear dest -- rule 21]; dest ptr must be wave-uniform (HW adds lane*16).
__device__ __forceinline__ void stage_half(
    const unsigned short* __restrict__ g, unsigned short* slot, int w, int lane)
{
    #pragma unroll
    for (int j = 0; j < 2; ++j) {
        const int idx = j * 512 + w * 64 + lane;
        const int r = idx >> 3, c = idx & 7;
        gload_lds16(g + (long)r * DIM + (c ^ (r & 7)) * 8,
                    slot + (j * 512 + w * 64) * 8);
    }
}

// ---------------------------------------------------------------- convert ---
__global__ __launch_bounds__(256) void convert_f32_bf16(
    const float* __restrict__ src, unsigned short* __restrict__ dst, long n)
{
    long i = ((long)blockIdx.x * 256 + threadIdx.x) * 8;
    if (i + 8 > n) return;
    f32x8 v = *(const f32x8*)(src + i);
    u16x8 o;
    #pragma unroll
    for (int j = 0; j < 8; ++j) o[j] = f2bf(v[j]);
    *(u16x8*)(dst + i) = o;
}

// ---------------------------------------------- 256^2 pipelined GEMM+LSE ---
__global__ __launch_bounds__(512, 2) void gemm_lse(
    const unsigned short* __restrict__ hA,    // [4096][2048] bf16 bits
    const unsigned short* __restrict__ Wb,    // [seg_rows][2048] bf16 bits
    float* __restrict__ part_m, float* __restrict__ part_s, int chunk0)
{
    __shared__ unsigned short A_lds[4][128 * 64];
    __shared__ unsigned short B_lds[4][128 * 64];
    __shared__ float red_m[256 * 4];
    __shared__ float red_s[256 * 4];

    const int tid  = threadIdx.x;
    const int lane = tid & 63;
    const int w    = tid >> 6;       // wave 0..7
    const int wm   = w >> 2;         // 0..1 : token half (128 rows)
    const int wn   = w & 3;          // 0..3 : vocab quarter (64 cols)

    // bijective XCD-aware remap (m204), token-fastest decode
    const int nwg  = gridDim.x;
    const int orig = blockIdx.x;
    const int q8 = nwg >> 3, r8 = nwg & 7;
    const int xcd = orig & 7;
    const int wg  = (xcd < r8 ? xcd * (q8 + 1) : r8 * (q8 + 1) + (xcd - r8) * q8)
                    + (orig >> 3);
    const int tok_blk = wg & (NTB - 1);
    const int voc_blk = wg >> 4;                 // NTB == 16

    const long arow0 = (long)tok_blk * BM;
    const long brow0 = (long)voc_blk * BM;
    const unsigned short* Ab = hA + arow0 * DIM;
    const unsigned short* Bb = Wb + brow0 * DIM;

    f32x4 acc[8][4];
    #pragma unroll
    for (int i = 0; i < 8; ++i)
        #pragma unroll
        for (int j = 0; j < 4; ++j)
            acc[i][j] = (f32x4){0.f, 0.f, 0.f, 0.f};

    // prologue: K-step 0 (A0,A1,B0,B1) + B(1); A(1) staged inside t=0.
    stage_half(Ab,                 &A_lds[0][0], w, lane);
    stage_half(Ab + 128 * DIM,     &A_lds[1][0], w, lane);
    stage_half(Bb,                 &B_lds[0][0], w, lane);
    stage_half(Bb + 128 * DIM,     &B_lds[1][0], w, lane);
    stage_half(Bb + 64,            &B_lds[2][0], w, lane);
    stage_half(Bb + 128 * DIM + 64,&B_lds[3][0], w, lane);
    asm volatile("s_waitcnt vmcnt(4)" ::: "memory");   // K-step 0 tiles ready
    bar();

    const int swz   = (lane & 7) << 4;        // read-side XOR (row&7 == lane&7)
    const int colb0 = (lane >> 4) * 16;       // kk byte col base
    const int lrow  = lane & 15;

#define LDA(DST, ROWBASE)                                                     \
    _Pragma("unroll")                                                         \
    for (int f = 0; f < 2; ++f)                                               \
        _Pragma("unroll")                                                     \
        for (int kk = 0; kk < 2; ++kk)                                        \
            DST[f][kk] = *(const bf16x8*)(Ah + ((ROWBASE) + f * 16 + lrow) *  \
                                          128 + ((kk * 64 + colb0) ^ swz));

#define MFMA_CLUST(AF, Q)                                                     \
    __builtin_amdgcn_s_setprio(1);                                            \
    _Pragma("unroll")                                                         \
    for (int kk = 0; kk < 2; ++kk)                                            \
        _Pragma("unroll")                                                     \
        for (int f = 0; f < 2; ++f)                                           \
            _Pragma("unroll")                                                 \
            for (int n = 0; n < 4; ++n)                                       \
                acc[(Q) * 2 + f][n] = __builtin_amdgcn_mfma_f32_16x16x32_bf16(\
                    AF[f][kk], bfr[n][kk], acc[(Q) * 2 + f][n], 0, 0, 0);     \
    __builtin_amdgcn_s_setprio(0);

    for (int t = 0; t < NT; ++t) {
        const int p  = (t & 1) * 2;
        const int pn = ((t + 1) & 1) * 2;
        const char* Ah = (const char*)&A_lds[p + wm][0];
        const char* Bh = (const char*)&B_lds[p + (wn >> 1)][0];
        const int brB = (wn & 1) * 64;

        bf16x8 af0[2][2], af1[2][2], bfr[4][2];

        // ---- region 1: reads q0, B-frags, reads q1; A stages; MFMA q0 ----
        LDA(af0, 0)
        #pragma unroll
        for (int n = 0; n < 4; ++n)
            #pragma unroll
            for (int kk = 0; kk < 2; ++kk)
                bfr[n][kk] = *(const bf16x8*)(Bh + (brB + n * 16 + lrow) * 128 +
                                              ((kk * 64 + colb0) ^ swz));
        if (t + 1 < NT)
            stage_half(Ab + (t + 1) * 64, &A_lds[pn + 0][0], w, lane);
        LDA(af1, 32)
        if (t + 1 < NT)
            stage_half(Ab + 128 * DIM + (t + 1) * 64, &A_lds[pn + 1][0], w, lane);
        MFMA_CLUST(af0, 0)
        bar();   // mid: all waves' B reads consumed; B slots restageable

        // ---- region 2: reads q2 | stage B0 | MFMA q1 | reads q3 | stage B1
        //                | MFMA q2 | MFMA q3 ----
        LDA(af0, 64)
        if (t + 2 < NT)
            stage_half(Bb + (t + 2) * 64, &B_lds[p + 0][0], w, lane);
        MFMA_CLUST(af1, 1)
        LDA(af1, 96)
        if (t + 2 < NT)
            stage_half(Bb + 128 * DIM + (t + 2) * 64, &B_lds[p + 1][0], w, lane);
        MFMA_CLUST(af0, 2)
        MFMA_CLUST(af1, 3)

        // boundary: A(t+1)+all older complete; B(t+2) halves may float.
        if (t < NT - 2) asm volatile("s_waitcnt vmcnt(4)" ::: "memory");
        else            asm volatile("s_waitcnt vmcnt(0)" ::: "memory");
        bar();
    }
#undef LDA
#undef MFMA_CLUST

    // ---- epilogue: per-token (max, sumexp) over this block's 256 cols ----
    // C frag layout: row = mf*16 + (lane>>4)*4 + reg, col = nf*16 + (lane&15).
    #pragma unroll
    for (int mf = 0; mf < 8; ++mf) {
        #pragma unroll
        for (int r = 0; r < 4; ++r) {
            float v0 = acc[mf][0][r], v1 = acc[mf][1][r];
            float v2 = acc[mf][2][r], v3 = acc[mf][3][r];
            float mx = fmaxf(fmaxf(v0, v1), fmaxf(v2, v3));
            #pragma unroll
            for (int msk = 1; msk < 16; msk <<= 1)
                mx = fmaxf(mx, __shfl_xor(mx, msk, 64));
            float se = __expf(v0 - mx) + __expf(v1 - mx) +
                       __expf(v2 - mx) + __expf(v3 - mx);
            #pragma unroll
            for (int msk = 1; msk < 16; msk <<= 1)
                se += __shfl_xor(se, msk, 64);
            if ((lane & 15) == 0) {
                const int row = wm * 128 + mf * 16 + (lane >> 4) * 4 + r;
                red_m[row * 4 + wn] = mx;
                red_s[row * 4 + wn] = se;
            }
        }
    }
    __syncthreads();
    if (tid < 256) {
        float M = red_m[tid * 4], S = red_s[tid * 4];
        #pragma unroll
        for (int j = 1; j < 4; ++j) {
            const float m2 = red_m[tid * 4 + j], s2 = red_s[tid * 4 + j];
            const float Mn = fmaxf(M, m2);
            S = S * __expf(M - Mn) + s2 * __expf(m2 - Mn);
            M = Mn;
        }
        part_m[(arow0 + tid) * NCH + chunk0 + voc_blk] = M;
        part_s[(arow0 + tid) * NCH + chunk0 + voc_blk] = S;
    }
}

// ------------------------------------------------------- exact label dot ----
__global__ __launch_bounds__(256) void label_dot(
    const float* __restrict__ h, const float* __restrict__ W,
    const void* __restrict__ labels, float* __restrict__ lab_logit)
{
    bool is64 = true;
    #pragma unroll
    for (int i = 0; i < 8; ++i) {
        long long v = ((const long long*)labels)[i];
        if (v < 0 || v >= VOCAB) is64 = false;
    }
    const int t = blockIdx.x;
    const int lab = is64 ? (int)((const long long*)labels)[t]
                         : ((const int*)labels)[t];
    const float4* hp = (const float4*)(h + (long)t * DIM);
    const float4* wp = (const float4*)(W + (long)lab * DIM);
    float s = 0.f;
    #pragma unroll
    for (int j = 0; j < 2; ++j) {
        const float4 a = hp[threadIdx.x + j * 256];
        const float4 b = wp[threadIdx.x + j * 256];
        s += a.x * b.x + a.y * b.y + a.z * b.z + a.w * b.w;
    }
    #pragma unroll
    for (int msk = 1; msk < 64; msk <<= 1) s += __shfl_xor(s, msk, 64);
    __shared__ float ps[4];
    if ((threadIdx.x & 63) == 0) ps[threadIdx.x >> 6] = s;
    __syncthreads();
    if (threadIdx.x == 0) lab_logit[t] = ps[0] + ps[1] + ps[2] + ps[3];
}

// ---------------------------------------------------- per-token LSE merge ---
__global__ __launch_bounds__(256) void finalize_nll(
    const float* __restrict__ part_m, const float* __restrict__ part_s,
    const float* __restrict__ lab_logit, const float* __restrict__ wts,
    float* __restrict__ wnll)
{
    const int t    = blockIdx.x * 4 + (threadIdx.x >> 6);  // one wave / token
    const int lane = threadIdx.x & 63;
    float m = -3.4e38f, s = 0.f;
    #pragma unroll
    for (int j = 0; j < 4; ++j) {
        const int c = j * 64 + lane;
        const float pm = part_m[(long)t * NCH + c];
        const float ps = part_s[(long)t * NCH + c];
        const float M = fmaxf(m, pm);
        s = s * __expf(m - M) + ps * __expf(pm - M);
        m = M;
    }
    #pragma unroll
    for (int msk = 1; msk < 64; msk <<= 1) {
        const float om = __shfl_xor(m, msk, 64);
        const float os = __shfl_xor(s, msk, 64);
        const float M = fmaxf(m, om);
        s = s * __expf(m - M) + os * __expf(om - M);
        m = M;
    }
    if (lane == 0) {
        const float lse = m + logf(s);
        wnll[t] = wts[t] * (lse - lab_logit[t]);
    }
}

// -------------------------------------------------- deterministic reduce ----
__global__ __launch_bounds__(1024) void final_reduce(
    const float* __restrict__ wnll, const float* __restrict__ wts,
    float* __restrict__ out)
{
    float a = 0.f, b = 0.f;
    #pragma unroll
    for (int j = 0; j < 4; ++j) {
        const int i = threadIdx.x + j * 1024;
        a += wnll[i];
        b += wts[i];
    }
    #pragma unroll
    for (int msk = 1; msk < 64; msk <<= 1) {
        a += __shfl_xor(a, msk, 64);
        b += __shfl_xor(b, msk, 64);
    }
    __shared__ float pa[16], pb[16];
    if ((threadIdx.x & 63) == 0) {
        pa[threadIdx.x >> 6] = a;
        pb[threadIdx.x >> 6] = b;
    }
    __syncthreads();
    if (threadIdx.x == 0) {
        float A = 0.f, B = 0.f;
        #pragma unroll
        for (int i = 0; i < 16; ++i) { A += pa[i]; B += pb[i]; }
        out[0] = A / B;
    }
}

// ----------------------------------------------------------------- launch ---
extern "C" void kernel_launch(void* const* d_in, const int* in_sizes, int n_in,
                              void* d_out, int out_size, void* d_ws, size_t ws_size,
                              hipStream_t stream)
{
    const float* h      = (const float*)d_in[0];
    const void*  labels = d_in[1];
    const float* wts    = (const float*)d_in[2];
    const float* W      = (const float*)d_in[3];
    float* out = (float*)d_out;

    char* ws = (char*)d_ws;
    unsigned short* h_bf      = (unsigned short*)(ws);                 // 16 MB
    float*          part_m    = (float*)(ws + (16u << 20));            //  4 MB
    float*          part_s    = (float*)(ws + (24u << 20));            //  4 MB
    float*          lab_logit = (float*)(ws + (32u << 20));            // 16 KB
    float*          wnll      = (float*)(ws + (32u << 20) + 16384);    // 16 KB
    unsigned short* wseg      = (unsigned short*)(ws + (32u << 20) + 32768);
    const size_t base = (size_t)(32u << 20) + 32768;

    long segmax = 0;
    if (ws_size > base) segmax = (long)((ws_size - base) / ((size_t)DIM * 2));
    segmax &= ~255L;
    if (segmax > VOCAB) segmax = VOCAB;
    if (segmax < 256)   segmax = 256;   // require ws_size >= ~34 MB

    // 0) h -> bf16
    convert_f32_bf16<<<(N_TOK * DIM) / (256 * 8), 256, 0, stream>>>(
        h, h_bf, (long)N_TOK * DIM);

    // 1) segmented W conversion + fused GEMM/LSE partials
    for (long v0 = 0; v0 < VOCAB; v0 += segmax) {
        const long rows = (VOCAB - v0) < segmax ? (VOCAB - v0) : segmax;
        convert_f32_bf16<<<(int)(rows * DIM / (256 * 8)), 256, 0, stream>>>(
            W + v0 * DIM, wseg, rows * (long)DIM);
        const int nwg = (int)(rows / BM) * NTB;
        gemm_lse<<<nwg, 512, 0, stream>>>(h_bf, wseg, part_m, part_s,
                                          (int)(v0 / BN));
    }

    // 2) exact label logits (fp32)
    label_dot<<<N_TOK, 256, 0, stream>>>(h, W, labels, lab_logit);

    // 3) per-token LSE merge -> w*nll
    finalize_nll<<<N_TOK / 4, 256, 0, stream>>>(part_m, part_s, lab_logit,
                                                wts, wnll);

    // 4) weighted mean
    final_reduce<<<1, 1024, 0, stream>>>(wnll, wts, out);
}

// Round 5
// 1503.429 us; speedup vs baseline: 1.2967x; 1.0809x over previous
//
#include <hip/hip_runtime.h>

// ---------------------------------------------------------------------------
// FusedSparseLMHead: weighted-mean CE over h @ W^T without materializing logits.
//   h: [4096, 2048] f32, W: [65536, 2048] f32, labels: [4096] int, w: [4096] f32
// Round 5: 256x256 ring GEMM with 32x32x16 MFMA (half the MFMA instr count),
//   t-loop unrolled x2 (compile-time LDS slot bases -> ds offsets fold to
//   immediates), boundary wait vmcnt(2) (fixes r4's latent B(t+1) race).
//   Ring: A(t+1) staged region 1, B(t+2) staged region 2; 2 barriers/K-step.
// ---------------------------------------------------------------------------

typedef __attribute__((ext_vector_type(8)))  short bf16x8;
typedef __attribute__((ext_vector_type(16))) float f32x16;
typedef __attribute__((ext_vector_type(8)))  float f32x8;
typedef __attribute__((ext_vector_type(8)))  unsigned short u16x8;

#define N_TOK 4096
#define DIM   2048
#define VOCAB 65536
#define BM    256
#define BN    256
#define BK    64
#define NT    (DIM / BK)     // 32 K-steps
#define NCH   (VOCAB / BN)   // 256 vocab chunks
#define NTB   (N_TOK / BM)   // 16 token blocks
#define SLOT  8192           // shorts per 128x64 half-tile slot (16 KB)

__device__ __forceinline__ unsigned short f2bf(float x) {
    unsigned u = __float_as_uint(x);
    unsigned r = (u + 0x7fffu + ((u >> 16) & 1u)) >> 16;   // RNE
    return (unsigned short)r;
}

__device__ __forceinline__ void gload_lds16(const void* g, void* l) {
    __builtin_amdgcn_global_load_lds(
        (const __attribute__((address_space(1))) void*)g,
        (__attribute__((address_space(3))) void*)l, 16, 0, 0);
}

__device__ __forceinline__ void bar() {
    asm volatile("" ::: "memory");
    __builtin_amdgcn_s_barrier();
    asm volatile("" ::: "memory");
}

// stage one 128x64 half-tile (16 KB): 512 threads x 2 loads x 16 B.
// LDS chunk c of row r receives global chunk (c ^ (r&7))  [pre-swizzled src,
// linear dest -- rule 21]; dest ptr must be wave-uniform (HW adds lane*16).
__device__ __forceinline__ void stage_half(
    const unsigned short* __restrict__ g, unsigned short* slot, int w, int lane)
{
    #pragma unroll
    for (int j = 0; j < 2; ++j) {
        const int idx = j * 512 + w * 64 + lane;
        const int r = idx >> 3, c = idx & 7;
        gload_lds16(g + (long)r * DIM + (c ^ (r & 7)) * 8,
                    slot + (j * 512 + w * 64) * 8);
    }
}

// ---------------------------------------------------------------- convert ---
__global__ __launch_bounds__(256) void convert_f32_bf16(
    const float* __restrict__ src, unsigned short* __restrict__ dst, long n)
{
    long i = ((long)blockIdx.x * 256 + threadIdx.x) * 8;
    if (i + 8 > n) return;
    f32x8 v = *(const f32x8*)(src + i);
    u16x8 o;
    #pragma unroll
    for (int j = 0; j < 8; ++j) o[j] = f2bf(v[j]);
    *(u16x8*)(dst + i) = o;
}

// ---------------------------------------------- 256^2 ring GEMM+LSE (32x32) -
__global__ __launch_bounds__(512, 2) void gemm_lse(
    const unsigned short* __restrict__ hA,    // [4096][2048] bf16 bits
    const unsigned short* __restrict__ Wb,    // [seg_rows][2048] bf16 bits
    float* __restrict__ part_m, float* __restrict__ part_s, int chunk0)
{
    __shared__ unsigned short A_lds[4 * SLOT];
    __shared__ unsigned short B_lds[4 * SLOT];
    __shared__ float red_m[256 * 4];
    __shared__ float red_s[256 * 4];

    const int tid  = threadIdx.x;
    const int lane = tid & 63;
    const int w    = tid >> 6;       // wave 0..7
    const int wm   = w >> 2;         // 0..1 : token half (128 rows)
    const int wn   = w & 3;          // 0..3 : vocab quarter (64 cols)

    // bijective XCD-aware remap (m204), token-fastest decode
    const int nwg  = gridDim.x;
    const int orig = blockIdx.x;
    const int q8 = nwg >> 3, r8 = nwg & 7;
    const int xcd = orig & 7;
    const int wg  = (xcd < r8 ? xcd * (q8 + 1) : r8 * (q8 + 1) + (xcd - r8) * q8)
                    + (orig >> 3);
    const int tok_blk = wg & (NTB - 1);
    const int voc_blk = wg >> 4;                 // NTB == 16

    const long arow0 = (long)tok_blk * BM;
    const long brow0 = (long)voc_blk * BM;
    const unsigned short* Ab = hA + arow0 * DIM;
    const unsigned short* Bb = Wb + brow0 * DIM;

    f32x16 acc[4][2];
    #pragma unroll
    for (int i = 0; i < 4; ++i)
        #pragma unroll
        for (int j = 0; j < 2; ++j)
            #pragma unroll
            for (int e = 0; e < 16; ++e)
                acc[i][j][e] = 0.f;

    // prologue: K-tile 0 (A0,A1,B0,B1) + B(1); A(1) staged inside t=0.
    stage_half(Ab,                  A_lds,            w, lane);
    stage_half(Ab + 128 * DIM,      A_lds + SLOT,     w, lane);
    stage_half(Bb,                  B_lds,            w, lane);
    stage_half(Bb + 128 * DIM,      B_lds + SLOT,     w, lane);
    stage_half(Bb + 64,             B_lds + 2 * SLOT, w, lane);
    stage_half(Bb + 128 * DIM + 64, B_lds + 3 * SLOT, w, lane);
    asm volatile("s_waitcnt vmcnt(4)" ::: "memory");   // K-tile 0 landed
    bar();

    const int swz  = (lane & 7) << 4;        // read-side XOR (row&7 == lane&7)
    const int hi16 = (lane >> 5) << 4;       // k-group byte offset
    const int arw  = (lane & 31) * 128;      // A/B row byte offset in slot
    const int brw  = ((wn & 1) * 64 + (lane & 31)) * 128;

// A-frag reads: quadrant Q rows [Q*32, Q*32+32), one b128 per kk (K=16 slice).
#define LDA(DST, Q, P)                                                        \
    _Pragma("unroll")                                                         \
    for (int kk = 0; kk < 4; ++kk)                                            \
        DST[kk] = *(const bf16x8*)((const char*)A_lds + ((P) + wm) * 16384 +  \
                   (Q) * 32 * 128 + arw + ((kk * 32 + hi16) ^ swz));

#define LDB(P)                                                                \
    _Pragma("unroll")                                                         \
    for (int nf = 0; nf < 2; ++nf)                                            \
        _Pragma("unroll")                                                     \
        for (int kk = 0; kk < 4; ++kk)                                        \
            bfr[nf][kk] = *(const bf16x8*)((const char*)B_lds +               \
                ((P) + (wn >> 1)) * 16384 + nf * 32 * 128 + brw +             \
                ((kk * 32 + hi16) ^ swz));

#define MFMA8(AF, Q)                                                          \
    __builtin_amdgcn_s_setprio(1);                                            \
    _Pragma("unroll")                                                         \
    for (int kk = 0; kk < 4; ++kk)                                            \
        _Pragma("unroll")                                                     \
        for (int nf = 0; nf < 2; ++nf)                                        \
            acc[Q][nf] = __builtin_amdgcn_mfma_f32_32x32x16_bf16(             \
                AF[kk], bfr[nf][kk], acc[Q][nf], 0, 0, 0);                    \
    __builtin_amdgcn_s_setprio(0);

// One K-step: P = this tile's slot base (compile-time), Pn = other parity.
// region1: {LDA q0, LDB, stage A0(t+1), LDA q1, stage A1(t+1), MFMA q0} bar
// region2: {LDA q2, stage B0(t+2), MFMA q1, LDA q3, stage B1(t+2),
//           MFMA q2, MFMA q3} vmcnt(2) bar
// vmcnt(2) proof: outstanding at boundary(t) = [B1(t+1)?2, A(t+1)4, B(t+2)4];
//   wait<=2 -> B(t+1),A(t+1),B0(t+2) landed; only B1(t+2) floats, which is
//   first read in region1 of t+2, protected by boundary(t+1)'s wait.
#define KSTEP(P, Pn, t)                                                       \
    {                                                                         \
        bf16x8 af[4], ag[4], bfr[2][4];                                       \
        LDA(af, 0, P)                                                         \
        LDB(P)                                                                \
        if ((t) + 1 < NT)                                                     \
            stage_half(Ab + ((t) + 1) * 64, A_lds + (Pn) * SLOT, w, lane);    \
        LDA(ag, 1, P)                                                         \
        if ((t) + 1 < NT)                                                     \
            stage_half(Ab + 128 * DIM + ((t) + 1) * 64,                       \
                       A_lds + ((Pn) + 1) * SLOT, w, lane);                   \
        MFMA8(af, 0)                                                          \
        bar();                                                                \
        LDA(af, 2, P)                                                         \
        if ((t) + 2 < NT)                                                     \
            stage_half(Bb + ((t) + 2) * 64, B_lds + (P) * SLOT, w, lane);     \
        MFMA8(ag, 1)                                                          \
        LDA(ag, 3, P)                                                         \
        if ((t) + 2 < NT)                                                     \
            stage_half(Bb + 128 * DIM + ((t) + 2) * 64,                       \
                       B_lds + ((P) + 1) * SLOT, w, lane);                    \
        MFMA8(af, 2)                                                          \
        MFMA8(ag, 3)                                                          \
        if ((t) < NT - 2) { asm volatile("s_waitcnt vmcnt(2)" ::: "memory"); }\
        else              { asm volatile("s_waitcnt vmcnt(0)" ::: "memory"); }\
        bar();                                                                \
    }

    for (int t = 0; t < NT; t += 2) {
        KSTEP(0, 2, t)
        KSTEP(2, 0, t + 1)
    }
#undef LDA
#undef LDB
#undef MFMA8
#undef KSTEP

    // ---- epilogue: per-token (max, sumexp) over this block's 256 cols ----
    // 32x32 C/D: col = lane&31, row = (reg&3) + 8*(reg>>2) + 4*(lane>>5).
    #pragma unroll
    for (int q = 0; q < 4; ++q) {
        #pragma unroll
        for (int rg = 0; rg < 16; ++rg) {
            float v0 = acc[q][0][rg], v1 = acc[q][1][rg];
            float mx = fmaxf(v0, v1);
            #pragma unroll
            for (int msk = 1; msk < 32; msk <<= 1)
                mx = fmaxf(mx, __shfl_xor(mx, msk, 64));
            float se = __expf(v0 - mx) + __expf(v1 - mx);
            #pragma unroll
            for (int msk = 1; msk < 32; msk <<= 1)
                se += __shfl_xor(se, msk, 64);
            if ((lane & 31) == 0) {
                const int row = wm * 128 + q * 32 + (rg & 3) + 8 * (rg >> 2) +
                                4 * (lane >> 5);
                red_m[row * 4 + wn] = mx;
                red_s[row * 4 + wn] = se;
            }
        }
    }
    __syncthreads();
    if (tid < 256) {
        float M = red_m[tid * 4], S = red_s[tid * 4];
        #pragma unroll
        for (int j = 1; j < 4; ++j) {
            const float m2 = red_m[tid * 4 + j], s2 = red_s[tid * 4 + j];
            const float Mn = fmaxf(M, m2);
            S = S * __expf(M - Mn) + s2 * __expf(m2 - Mn);
            M = Mn;
        }
        part_m[(arow0 + tid) * NCH + chunk0 + voc_blk] = M;
        part_s[(arow0 + tid) * NCH + chunk0 + voc_blk] = S;
    }
}

// ------------------------------------------------------- exact label dot ----
__global__ __launch_bounds__(256) void label_dot(
    const float* __restrict__ h, const float* __restrict__ W,
    const void* __restrict__ labels, float* __restrict__ lab_logit)
{
    bool is64 = true;
    #pragma unroll
    for (int i = 0; i < 8; ++i) {
        long long v = ((const long long*)labels)[i];
        if (v < 0 || v >= VOCAB) is64 = false;
    }
    const int t = blockIdx.x;
    const int lab = is64 ? (int)((const long long*)labels)[t]
                         : ((const int*)labels)[t];
    const float4* hp = (const float4*)(h + (long)t * DIM);
    const float4* wp = (const float4*)(W + (long)lab * DIM);
    float s = 0.f;
    #pragma unroll
    for (int j = 0; j < 2; ++j) {
        const float4 a = hp[threadIdx.x + j * 256];
        const float4 b = wp[threadIdx.x + j * 256];
        s += a.x * b.x + a.y * b.y + a.z * b.z + a.w * b.w;
    }
    #pragma unroll
    for (int msk = 1; msk < 64; msk <<= 1) s += __shfl_xor(s, msk, 64);
    __shared__ float ps[4];
    if ((threadIdx.x & 63) == 0) ps[threadIdx.x >> 6] = s;
    __syncthreads();
    if (threadIdx.x == 0) lab_logit[t] = ps[0] + ps[1] + ps[2] + ps[3];
}

// ---------------------------------------------------- per-token LSE merge ---
__global__ __launch_bounds__(256) void finalize_nll(
    const float* __restrict__ part_m, const float* __restrict__ part_s,
    const float* __restrict__ lab_logit, const float* __restrict__ wts,
    float* __restrict__ wnll)
{
    const int t    = blockIdx.x * 4 + (threadIdx.x >> 6);  // one wave / token
    const int lane = threadIdx.x & 63;
    float m = -3.4e38f, s = 0.f;
    #pragma unroll
    for (int j = 0; j < 4; ++j) {
        const int c = j * 64 + lane;
        const float pm = part_m[(long)t * NCH + c];
        const float ps = part_s[(long)t * NCH + c];
        const float M = fmaxf(m, pm);
        s = s * __expf(m - M) + ps * __expf(pm - M);
        m = M;
    }
    #pragma unroll
    for (int msk = 1; msk < 64; msk <<= 1) {
        const float om = __shfl_xor(m, msk, 64);
        const float os = __shfl_xor(s, msk, 64);
        const float M = fmaxf(m, om);
        s = s * __expf(m - M) + os * __expf(om - M);
        m = M;
    }
    if (lane == 0) {
        const float lse = m + logf(s);
        wnll[t] = wts[t] * (lse - lab_logit[t]);
    }
}

// -------------------------------------------------- deterministic reduce ----
__global__ __launch_bounds__(1024) void final_reduce(
    const float* __restrict__ wnll, const float* __restrict__ wts,
    float* __restrict__ out)
{
    float a = 0.f, b = 0.f;
    #pragma unroll
    for (int j = 0; j < 4; ++j) {
        const int i = threadIdx.x + j * 1024;
        a += wnll[i];
        b += wts[i];
    }
    #pragma unroll
    for (int msk = 1; msk < 64; msk <<= 1) {
        a += __shfl_xor(a, msk, 64);
        b += __shfl_xor(b, msk, 64);
    }
    __shared__ float pa[16], pb[16];
    if ((threadIdx.x & 63) == 0) {
        pa[threadIdx.x >> 6] = a;
        pb[threadIdx.x >> 6] = b;
    }
    __syncthreads();
    if (threadIdx.x == 0) {
        float A = 0.f, B = 0.f;
        #pragma unroll
        for (int i = 0; i < 16; ++i) { A += pa[i]; B += pb[i]; }
        out[0] = A / B;
    }
}

// ----------------------------------------------------------------- launch ---
extern "C" void kernel_launch(void* const* d_in, const int* in_sizes, int n_in,
                              void* d_out, int out_size, void* d_ws, size_t ws_size,
                              hipStream_t stream)
{
    const float* h      = (const float*)d_in[0];
    const void*  labels = d_in[1];
    const float* wts    = (const float*)d_in[2];
    const float* W      = (const float*)d_in[3];
    float* out = (float*)d_out;

    char* ws = (char*)d_ws;
    unsigned short* h_bf      = (unsigned short*)(ws);                 // 16 MB
    float*          part_m    = (float*)(ws + (16u << 20));            //  4 MB
    float*          part_s    = (float*)(ws + (24u << 20));            //  4 MB
    float*          lab_logit = (float*)(ws + (32u << 20));            // 16 KB
    float*          wnll      = (float*)(ws + (32u << 20) + 16384);    // 16 KB
    unsigned short* wseg      = (unsigned short*)(ws + (32u << 20) + 32768);
    const size_t base = (size_t)(32u << 20) + 32768;

    long segmax = 0;
    if (ws_size > base) segmax = (long)((ws_size - base) / ((size_t)DIM * 2));
    segmax &= ~255L;
    if (segmax > VOCAB) segmax = VOCAB;
    if (segmax < 256)   segmax = 256;   // require ws_size >= ~34 MB

    // 0) h -> bf16
    convert_f32_bf16<<<(N_TOK * DIM) / (256 * 8), 256, 0, stream>>>(
        h, h_bf, (long)N_TOK * DIM);

    // 1) segmented W conversion + fused GEMM/LSE partials
    for (long v0 = 0; v0 < VOCAB; v0 += segmax) {
        const long rows = (VOCAB - v0) < segmax ? (VOCAB - v0) : segmax;
        convert_f32_bf16<<<(int)(rows * DIM / (256 * 8)), 256, 0, stream>>>(
            W + v0 * DIM, wseg, rows * (long)DIM);
        const int nwg = (int)(rows / BM) * NTB;
        gemm_lse<<<nwg, 512, 0, stream>>>(h_bf, wseg, part_m, part_s,
                                          (int)(v0 / BN));
    }

    // 2) exact label logits (fp32)
    label_dot<<<N_TOK, 256, 0, stream>>>(h, W, labels, lab_logit);

    // 3) per-token LSE merge -> w*nll
    finalize_nll<<<N_TOK / 4, 256, 0, stream>>>(part_m, part_s, lab_logit,
                                                wts, wnll);

    // 4) weighted mean
    final_reduce<<<1, 1024, 0, stream>>>(wnll, wts, out);
}